// Round 10
// baseline (182.513 us; speedup 1.0000x reference)
//
#include <hip/hip_runtime.h>
#include <hip/hip_bf16.h>
#include <cstdint>

#define EMBED   1024
#define NHEADS  16
#define HDIM    64
#define SEQ     2048
#define BSZ     2
#define MTOT    (BSZ*SEQ)   // 4096
#define NCLS    1000
#define NPAD    1024

typedef __attribute__((ext_vector_type(8))) short short8;
typedef __attribute__((ext_vector_type(4))) short short4v;
typedef __attribute__((ext_vector_type(4))) float float4v;

__device__ __forceinline__ void storeC(float* p, float v) { *p = v; }
__device__ __forceinline__ void storeC(__hip_bfloat16* p, float v) { *p = __float2bfloat16(v); }

__device__ __forceinline__ unsigned packbf2(float a, float b) {
    __hip_bfloat16 ha = __float2bfloat16(a), hb = __float2bfloat16(b);
    unsigned short ua, ub;
    __builtin_memcpy(&ua, &ha, 2); __builtin_memcpy(&ub, &hb, 2);
    return (unsigned)ua | ((unsigned)ub << 16);
}
// 8B-aligned LDS fragment load (rows stride 132 bf16 = 264 B)
__device__ __forceinline__ short8 lds8u(const __hip_bfloat16* p) {
    union { uint2 u[2]; short8 s; } v;
    v.u[0] = *(const uint2*)p;
    v.u[1] = *(const uint2*)(p + 4);
    return v.s;
}

// ---------------------------------------------------------------------------
// Convert fp32 x, W_in to bf16 ws copies; zero G. (W_out handled in weff.)
// ---------------------------------------------------------------------------
#define XN4  ((MTOT*EMBED)/4)    // 1,048,576
#define WN4  ((EMBED*EMBED)/4)   // 262,144
#define GN4  (32*64*64/4)        // 32,768
__global__ __launch_bounds__(256)
void conv_inputs(const float* __restrict__ x, const float* __restrict__ Win,
                 __hip_bfloat16* __restrict__ xb, __hip_bfloat16* __restrict__ Winb,
                 float* __restrict__ G) {
    const long i4 = (long)blockIdx.x * 256 + threadIdx.x;  // float4 index
    if (i4 < GN4)
        *(float4v*)(G + i4 * 4) = (float4v){0.f, 0.f, 0.f, 0.f};
    float4v v;
    __hip_bfloat16* dst;
    if (i4 < XN4) {
        v = *(const float4v*)(x + i4 * 4);
        dst = xb + i4 * 4;
    } else {
        const long j = i4 - XN4;
        v = *(const float4v*)(Win + j * 4);
        dst = Winb + j * 4;
    }
    short4v o;
#pragma unroll
    for (int u = 0; u < 4; u++)
        ((__hip_bfloat16*)&o)[u] = __float2bfloat16(v[u]);
    *(short4v*)dst = o;
}

// ---------------------------------------------------------------------------
// GEMM: C[m][n] = sum_k A[m][k]*B[n][k] + bias[n]  (row-major, B^T input)
// NO LDS, NO BARRIERS: MFMA fragments loaded straight from global (lane
// reads 16B at row*K + k0 + lq*8 -- exactly the m89-verified A/B layout).
// Register ring of 4 K32-steps, fully unrolled (K=1024) so all k-offsets
// are immediates; prefetch distance 3 covers ~200cyc L2 latency. XCD-aware
// swizzle keeps each XCD's 3MB working set in its L2. 2 blocks/CU.
// DO_GRAM (GEMM1): transpose own bf16 P-tile into a private 17KB LDS and
// atomicAdd the local 64x64 Gram via 16 MFMA (n-tile == one head).
// ---------------------------------------------------------------------------
template <typename CT, bool DO_GRAM>
__global__ __launch_bounds__(256)
void gemm_bt_bias(const __hip_bfloat16* __restrict__ A,
                  const __hip_bfloat16* __restrict__ B,
                  const float* __restrict__ bias,
                  CT* __restrict__ C,
                  float* __restrict__ G,
                  int nstore, int cstride, long bstride) {
    __shared__ __hip_bfloat16 Pt[64 * 132];   // gram transpose only (DO_GRAM)

    const int t    = threadIdx.x;
    const int blk  = blockIdx.x;            // 0..511
    const int xcd  = blk & 7;
    const int j    = blk >> 3;              // 0..63
    const int bm   = (xcd * 4 + (j & 3)) * 128;
    const int bn   = (j >> 2) * 64;
    const __hip_bfloat16* Bb = B + (long)(bm >> 11) * bstride;
    const int wave = t >> 6, lane = t & 63;
    const int wm   = (wave & 1) * 64, wn = (wave >> 1) * 32;
    const int lrow = lane & 15, lq = lane >> 4;

    // per-lane fragment row bases (k advances by +32 elems per step)
    const __hip_bfloat16* ap[4];
    const __hip_bfloat16* bp[2];
#pragma unroll
    for (int i = 0; i < 4; i++)
        ap[i] = A + (long)(bm + wm + i * 16 + lrow) * EMBED + lq * 8;
#pragma unroll
    for (int i = 0; i < 2; i++)
        bp[i] = Bb + (long)(bn + wn + i * 16 + lrow) * EMBED + lq * 8;

    float4v acc[4][2];
#pragma unroll
    for (int i = 0; i < 4; i++)
#pragma unroll
        for (int jj = 0; jj < 2; jj++) acc[i][jj] = (float4v){0.f, 0.f, 0.f, 0.f};

#define LOADG(AD, BD, koff)                                                      \
    do {                                                                         \
        _Pragma("unroll")                                                        \
        for (int i = 0; i < 4; i++) (AD)[i] = *(const short8*)(ap[i] + (koff));  \
        _Pragma("unroll")                                                        \
        for (int i = 0; i < 2; i++) (BD)[i] = *(const short8*)(bp[i] + (koff));  \
    } while (0)

#define MFMA_STEP(AD, BD)                                                        \
    do {                                                                         \
        _Pragma("unroll")                                                        \
        for (int i = 0; i < 4; i++)                                              \
            _Pragma("unroll")                                                    \
            for (int jj = 0; jj < 2; jj++)                                       \
                acc[i][jj] = __builtin_amdgcn_mfma_f32_16x16x32_bf16(            \
                    (AD)[i], (BD)[jj], acc[i][jj], 0, 0, 0);                     \
    } while (0)

    short8 a[4][4];   // ring: 4 K32-steps x 4 A-frags
    short8 b[4][2];   //                  x 2 B-frags
    LOADG(a[0], b[0], 0);
    LOADG(a[1], b[1], 32);
    LOADG(a[2], b[2], 64);
    LOADG(a[3], b[3], 96);

#pragma unroll
    for (int s = 0; s < 32; s += 4) {           // K = 32 steps of 32
        MFMA_STEP(a[0], b[0]); if (s + 4 < 32) LOADG(a[0], b[0], (s + 4) * 32);
        MFMA_STEP(a[1], b[1]); if (s + 5 < 32) LOADG(a[1], b[1], (s + 5) * 32);
        MFMA_STEP(a[2], b[2]); if (s + 6 < 32) LOADG(a[2], b[2], (s + 6) * 32);
        MFMA_STEP(a[3], b[3]); if (s + 7 < 32) LOADG(a[3], b[3], (s + 7) * 32);
    }
#undef LOADG
#undef MFMA_STEP

    // epilogue: C/D layout col=lane&15, row=lq*4+reg
    float bv[2];
#pragma unroll
    for (int jj = 0; jj < 2; jj++) {
        const int gn = bn + wn + jj * 16 + lrow;
        bv[jj] = (gn < nstore) ? bias[gn] : 0.f;
    }

    if (DO_GRAM) {
        // transpose this block's bf16 P-tile into LDS: Pt[n 0..63][m 0..127]
#pragma unroll
        for (int i = 0; i < 4; i++) {
            const int m0 = wm + i * 16 + lq * 4;
#pragma unroll
            for (int jj = 0; jj < 2; jj++) {
                const int n = wn + jj * 16 + lrow;
                unsigned* dst = (unsigned*)(Pt + n * 132 + m0);
                dst[0] = packbf2(acc[i][jj][0] + bv[jj], acc[i][jj][1] + bv[jj]);
                dst[1] = packbf2(acc[i][jj][2] + bv[jj], acc[i][jj][3] + bv[jj]);
            }
        }
        __syncthreads();
    }

    // global C stores (in flight while gram MFMA runs below)
#pragma unroll
    for (int i = 0; i < 4; i++) {
        const int gm0 = bm + wm + i * 16 + lq * 4;
#pragma unroll
        for (int jj = 0; jj < 2; jj++) {
            const int gn = bn + wn + jj * 16 + lrow;
            if (gn < nstore) {
#pragma unroll
                for (int r = 0; r < 4; r++)
                    storeC(&C[(long)(gm0 + r) * cstride + gn], acc[i][jj][r] + bv[jj]);
            }
        }
    }

    if (DO_GRAM) {
        float4v g4[4];
#pragma unroll
        for (int t2 = 0; t2 < 4; t2++) g4[t2] = (float4v){0.f, 0.f, 0.f, 0.f};
        const int d1l = wave * 16 + lrow;   // wave's d1 band (A-operand rows)
#pragma unroll
        for (int k0 = 0; k0 < 128; k0 += 32) {
            short8 af = lds8u(Pt + d1l * 132 + k0 + lq * 8);
#pragma unroll
            for (int t2 = 0; t2 < 4; t2++) {
                short8 bfr = lds8u(Pt + (t2 * 16 + lrow) * 132 + k0 + lq * 8);
                g4[t2] = __builtin_amdgcn_mfma_f32_16x16x32_bf16(af, bfr, g4[t2], 0, 0, 0);
            }
        }
        float* Gh = G + (long)((bm >> 11) * 16 + (bn >> 6)) * 4096;
        const int d1b = wave * 16 + lq * 4;
#pragma unroll
        for (int t2 = 0; t2 < 4; t2++) {
            const int d2 = t2 * 16 + lrow;
#pragma unroll
            for (int r = 0; r < 4; r++)
                atomicAdd(&Gh[(d1b + r) * 64 + d2], g4[t2][r]);
        }
    }
}

// ---------------------------------------------------------------------------
// Weff (MFMA): WeffT[b][n][64h+d1] = scale * sum_d Wout[n][d+64h] * G[b,h][d][d1]
// G symmetry -> both operands k-contiguous. Wout/G converted bf16 in LDS.
// ---------------------------------------------------------------------------
__global__ __launch_bounds__(256)
void weff_kernel(const float* __restrict__ Wout, const float* __restrict__ G,
                 __hip_bfloat16* __restrict__ WeffT) {
    const int n0 = blockIdx.x * 64;
    const int h  = blockIdx.y;
    const int b  = blockIdx.z;
    const float* Gh = G + (b * 16 + h) * 4096;

    __shared__ __hip_bfloat16 Wl[64 * 72];
    __shared__ __hip_bfloat16 Gl[64 * 72];
    const int t = threadIdx.x;

#pragma unroll
    for (int it = 0; it < 4; it++) {
        const int ci = it * 256 + t;
        const int r = ci >> 4, c4 = (ci & 15) * 4;
        float4v v = (float4v){0.f, 0.f, 0.f, 0.f};
        if (n0 + r < NCLS)
            v = *(const float4v*)(Wout + (long)(n0 + r) * EMBED + h * HDIM + c4);
        *(uint2*)(Wl + r * 72 + c4) = (uint2){packbf2(v[0], v[1]), packbf2(v[2], v[3])};
        float4v g = *(const float4v*)(Gh + r * 64 + c4);
        *(uint2*)(Gl + r * 72 + c4) = (uint2){packbf2(g[0], g[1]), packbf2(g[2], g[3])};
    }
    __syncthreads();

    const int wave = t >> 6, lane = t & 63;
    const int lrow = lane & 15, lq = lane >> 4;
    float4v acc[4];
#pragma unroll
    for (int jj = 0; jj < 4; jj++) acc[jj] = (float4v){0.f, 0.f, 0.f, 0.f};

#pragma unroll
    for (int k0 = 0; k0 < 64; k0 += 32) {
        short8 af = *(const short8*)(Wl + (wave * 16 + lrow) * 72 + k0 + lq * 8);
#pragma unroll
        for (int jj = 0; jj < 4; jj++) {
            short8 bfr = *(const short8*)(Gl + (jj * 16 + lrow) * 72 + k0 + lq * 8);
            acc[jj] = __builtin_amdgcn_mfma_f32_16x16x32_bf16(af, bfr, acc[jj], 0, 0, 0);
        }
    }

    const float scale = 1.0f / 32.0f;  // 1/sqrt(EMBED)
    __hip_bfloat16* Wt = WeffT + (long)b * EMBED * NPAD;
#pragma unroll
    for (int jj = 0; jj < 4; jj++) {
        const int d1 = jj * 16 + lrow;
#pragma unroll
        for (int r = 0; r < 4; r++) {
            const int n = n0 + wave * 16 + lq * 4 + r;
            Wt[(long)n * EMBED + h * HDIM + d1] = __float2bfloat16(acc[jj][r] * scale);
        }
    }
}

// ---------------------------------------------------------------------------
extern "C" void kernel_launch(void* const* d_in, const int* in_sizes, int n_in,
                              void* d_out, int out_size, void* d_ws, size_t ws_size,
                              hipStream_t stream) {
    const float* x     = (const float*)d_in[0];
    const float* W_in  = (const float*)d_in[1];
    const float* b_in  = (const float*)d_in[2];
    const float* W_out = (const float*)d_in[3];
    const float* b_out = (const float*)d_in[4];
    float* out = (float*)d_out;

    char* ws = (char*)d_ws;
    __hip_bfloat16* xb    = (__hip_bfloat16*)(ws);                 // 8 MiB
    __hip_bfloat16* Winb  = (__hip_bfloat16*)(ws + (8u  << 20));   // 2 MiB
    __hip_bfloat16* P     = (__hip_bfloat16*)(ws + (10u << 20));   // 8 MiB
    float*          G     = (float*)(ws + (18u << 20));            // 512 KiB
    __hip_bfloat16* WeffT = (__hip_bfloat16*)(ws + (19u << 20));   // 4 MiB (2 batches)

    // 1) fp32->bf16 converts + G zero
    conv_inputs<<<(XN4 + WN4) / 256, 256, 0, stream>>>(x, W_in, xb, Winb, G);
    // 2) P = x @ W_in^T + b_in  [4096x1024] bf16; fused per-tile Gram atomics
    gemm_bt_bias<__hip_bfloat16, true><<<512, 256, 0, stream>>>(
        xb, Winb, b_in, P, G, NPAD, NPAD, 0);
    // 3) WeffT[b] = scale * (G . Wout^T) per head block (MFMA)
    weff_kernel<<<dim3(16, 16, 2), 256, 0, stream>>>(W_out, G, WeffT);
    // 4) out = P @ WeffT^T + b_out  [4096x1000] fp32, batch-strided B
    gemm_bt_bias<float, false><<<512, 256, 0, stream>>>(
        P, WeffT, b_out, out, nullptr, NCLS, NCLS, (long)EMBED * NPAD);
}

// Round 12
// 127.247 us; speedup vs baseline: 1.4343x; 1.4343x over previous
//
#include <hip/hip_runtime.h>
#include <hip/hip_bf16.h>
#include <cstdint>

#define EMBED   1024
#define NHEADS  16
#define HDIM    64
#define SEQ     2048
#define BSZ     2
#define MTOT    (BSZ*SEQ)   // 4096
#define NCLS    1000
#define NPAD    1024

typedef __attribute__((ext_vector_type(8))) short short8;
typedef __attribute__((ext_vector_type(4))) short short4v;
typedef __attribute__((ext_vector_type(4))) float float4v;

typedef __attribute__((address_space(3))) unsigned lds_uint;
typedef __attribute__((address_space(1))) const unsigned gbl_uint;

__device__ __forceinline__ void gl2lds16(const void* g, void* l) {
    __builtin_amdgcn_global_load_lds((gbl_uint*)g, (lds_uint*)l, 16, 0, 0);
}

#define WAITVM4() asm volatile("s_waitcnt vmcnt(4)" ::: "memory")
#define WAITVM0() asm volatile("s_waitcnt vmcnt(0)" ::: "memory")
#define BAR()     asm volatile("s_barrier" ::: "memory")

__device__ __forceinline__ void storeC(float* p, float v) { *p = v; }
__device__ __forceinline__ void storeC(__hip_bfloat16* p, float v) { *p = __float2bfloat16(v); }

__device__ __forceinline__ unsigned packbf2(float a, float b) {
    __hip_bfloat16 ha = __float2bfloat16(a), hb = __float2bfloat16(b);
    unsigned short ua, ub;
    __builtin_memcpy(&ua, &ha, 2); __builtin_memcpy(&ub, &hb, 2);
    return (unsigned)ua | ((unsigned)ub << 16);
}
// 8B-aligned LDS fragment load (row stride 68 bf16 = 136 B)
__device__ __forceinline__ short8 lds8u(const __hip_bfloat16* p) {
    union { uint2 u[2]; short8 s; } v;
    v.u[0] = *(const uint2*)p;
    v.u[1] = *(const uint2*)(p + 4);
    return v.s;
}

// ---------------------------------------------------------------------------
// Convert fp32 x, W_in to bf16 ws copies. (No G zeroing -- no atomics now.)
// ---------------------------------------------------------------------------
#define XN4  ((MTOT*EMBED)/4)    // 1,048,576
#define WN4  ((EMBED*EMBED)/4)   // 262,144
__global__ __launch_bounds__(256)
void conv_inputs(const float* __restrict__ x, const float* __restrict__ Win,
                 __hip_bfloat16* __restrict__ xb, __hip_bfloat16* __restrict__ Winb) {
    const long i4 = (long)blockIdx.x * 256 + threadIdx.x;  // float4 index
    float4v v;
    __hip_bfloat16* dst;
    if (i4 < XN4) {
        v = *(const float4v*)(x + i4 * 4);
        dst = xb + i4 * 4;
    } else {
        const long j = i4 - XN4;
        v = *(const float4v*)(Win + j * 4);
        dst = Winb + j * 4;
    }
    short4v o;
#pragma unroll
    for (int u = 0; u < 4; u++)
        ((__hip_bfloat16*)&o)[u] = __float2bfloat16(v[u]);
    *(short4v*)dst = o;
}

// ---------------------------------------------------------------------------
// GEMM: C[m][n] = sum_k A[m][k]*B[n][k] + bias[n]  (row-major, B^T input)
// 64x64 tile, BK=64 -> 1024 blocks = 4 blocks/CU (deep inter-block overlap
// hides barrier drains; LDS 32KB x 4 = 128KB). XOR-swizzled LDS rows,
// double-buffered, raw s_barrier + vmcnt(4). XCD swizzle: each XCD owns
// 8 A-tiles (1MB) x all B-tiles (2MB) -> 3MB working set fits its 4MiB L2.
// Fully deterministic (no atomics anywhere).
// ---------------------------------------------------------------------------
template <typename CT>
__global__ __launch_bounds__(256, 4)
void gemm_bt_bias(const __hip_bfloat16* __restrict__ A,
                  const __hip_bfloat16* __restrict__ B,
                  const float* __restrict__ bias,
                  CT* __restrict__ C,
                  int nstore, int cstride, long bstride) {
    __shared__ __hip_bfloat16 As[2][64 * 64];   // 2 x 8 KiB
    __shared__ __hip_bfloat16 Bs[2][64 * 64];   // 2 x 8 KiB

    const int t    = threadIdx.x;
    const int blk  = blockIdx.x;            // 0..1023
    const int xcd  = blk & 7;
    const int j    = blk >> 3;              // 0..127
    const int bm   = (xcd * 8 + (j & 7)) * 64;
    const int bn   = (j >> 3) * 64;
    const __hip_bfloat16* Bb = B + (long)(bm >> 11) * bstride;
    const int wave = t >> 6, lane = t & 63;
    const int wm   = (wave & 1) * 32, wn = (wave >> 1) * 32;
    const int lrow = lane & 15, lq = lane >> 4;

    // staging map: chunk ci (512 of 16B per operand); LDS slot ci holds
    // global (row = ci>>3, k-chunk = (ci&7)^(row&7))
    const __hip_bfloat16* Arow[2];
    const __hip_bfloat16* Brow[2];
#pragma unroll
    for (int i = 0; i < 2; i++) {
        const int ci = i * 256 + t;
        const int r  = ci >> 3;
        const int sc = ((ci & 7) ^ (r & 7)) * 8;
        Arow[i] = A  + (long)(bm + r) * EMBED + sc;
        Brow[i] = Bb + (long)(bn + r) * EMBED + sc;
    }

    float4v acc[2][2];
#pragma unroll
    for (int i = 0; i < 2; i++)
#pragma unroll
        for (int jj = 0; jj < 2; jj++) acc[i][jj] = (float4v){0.f, 0.f, 0.f, 0.f};

    const int nIter = EMBED >> 6;   // 16

#define STAGE_TILE(k0, buf)                                                     \
    do {                                                                        \
        _Pragma("unroll")                                                       \
        for (int i = 0; i < 2; i++)                                             \
            gl2lds16(Arow[i] + (k0), (char*)As[buf] + (i * 256 + t) * 16);      \
        _Pragma("unroll")                                                       \
        for (int i = 0; i < 2; i++)                                             \
            gl2lds16(Brow[i] + (k0), (char*)Bs[buf] + (i * 256 + t) * 16);      \
    } while (0)

    STAGE_TILE(0, 0);

    for (int it = 0; it < nIter; ++it) {
        const int cur = it & 1, nxt = cur ^ 1;
        if (it + 1 < nIter) {
            STAGE_TILE((it + 1) << 6, nxt);
            WAITVM4();   // current tile's 4 loads done; prefetch in flight
        } else {
            WAITVM0();
        }
        BAR();           // tile `cur` staged for all waves

        const __hip_bfloat16* Ac = As[cur];
        const __hip_bfloat16* Bc = Bs[cur];
#pragma unroll
        for (int kk = 0; kk < 2; kk++) {
            short8 af[2], bf[2];
#pragma unroll
            for (int i = 0; i < 2; i++) {
                const int row = wm + i * 16 + lrow;
                const int sc  = (kk * 4 + lq) ^ (row & 7);
                af[i] = *(const short8*)(Ac + row * 64 + sc * 8);
            }
#pragma unroll
            for (int jj = 0; jj < 2; jj++) {
                const int row = wn + jj * 16 + lrow;
                const int sc  = (kk * 4 + lq) ^ (row & 7);
                bf[jj] = *(const short8*)(Bc + row * 64 + sc * 8);
            }
#pragma unroll
            for (int i = 0; i < 2; i++)
#pragma unroll
                for (int jj = 0; jj < 2; jj++)
                    acc[i][jj] = __builtin_amdgcn_mfma_f32_16x16x32_bf16(af[i], bf[jj], acc[i][jj], 0, 0, 0);
        }
        BAR();           // all waves done reading `cur` before it's overwritten
    }
#undef STAGE_TILE

    // epilogue: C/D layout col=lane&15, row=lq*4+reg
    float bv[2];
#pragma unroll
    for (int jj = 0; jj < 2; jj++) {
        const int gn = bn + wn + jj * 16 + lrow;
        bv[jj] = (gn < nstore) ? bias[gn] : 0.f;
    }
#pragma unroll
    for (int i = 0; i < 2; i++) {
        const int gm0 = bm + wm + i * 16 + lq * 4;
#pragma unroll
        for (int jj = 0; jj < 2; jj++) {
            const int gn = bn + wn + jj * 16 + lrow;
            if (gn < nstore) {
#pragma unroll
                for (int r = 0; r < 4; r++)
                    storeC(&C[(long)(gm0 + r) * cstride + gn], acc[i][jj][r] + bv[jj]);
            }
        }
    }
}

// ---------------------------------------------------------------------------
// gram64: DETERMINISTIC Gram partials, no atomics.
// 64 blocks: blk = (b*16+h)*2 + half. Each block owns 1024 seq rows of head h,
// stages 64-row chunks transposed into LDS (Pt[d][m], stride 68), accumulates
// its 64x64 partial via MFMA in registers (fixed order), writes Gpart[blk].
// ---------------------------------------------------------------------------
__global__ __launch_bounds__(256)
void gram64(const __hip_bfloat16* __restrict__ P, float* __restrict__ Gpart) {
    __shared__ __hip_bfloat16 Pt[64 * 68];   // [d][m], 8.5 KiB
    const int t    = threadIdx.x;
    const int blk  = blockIdx.x;             // 0..63
    const int bh   = blk >> 1;               // 0..31
    const int half = blk & 1;
    const int b    = bh >> 4, h = bh & 15;
    const int row0 = b * SEQ + half * 1024;

    const int wave = t >> 6, lane = t & 63;
    const int lrow = lane & 15, lq = lane >> 4;

    float4v g4[4];
#pragma unroll
    for (int t2 = 0; t2 < 4; t2++) g4[t2] = (float4v){0.f, 0.f, 0.f, 0.f};

    for (int c = 0; c < 16; c++) {           // 16 chunks of 64 rows
        // stage chunk transposed: 512 short8 loads, 2 per thread
#pragma unroll
        for (int i = 0; i < 2; i++) {
            const int ci = i * 256 + t;
            const int r = ci >> 3, c8 = (ci & 7) * 8;   // row-in-chunk, d-offset
            short8 v = *(const short8*)(P + (long)(row0 + c * 64 + r) * EMBED + h * HDIM + c8);
#pragma unroll
            for (int u = 0; u < 8; u++)
                Pt[(c8 + u) * 68 + r] = ((const __hip_bfloat16*)&v)[u];
        }
        __syncthreads();

#pragma unroll
        for (int k0 = 0; k0 < 64; k0 += 32) {
            short8 af = lds8u(Pt + (wave * 16 + lrow) * 68 + k0 + lq * 8);
#pragma unroll
            for (int t2 = 0; t2 < 4; t2++) {
                short8 bfr = lds8u(Pt + (t2 * 16 + lrow) * 68 + k0 + lq * 8);
                g4[t2] = __builtin_amdgcn_mfma_f32_16x16x32_bf16(af, bfr, g4[t2], 0, 0, 0);
            }
        }
        __syncthreads();
    }

    // store partial: C/D layout col=lane&15 (d2), row=lq*4+reg (within d1 band)
    float* Gh = Gpart + (long)blk * 4096;
    const int d1b = wave * 16 + lq * 4;
#pragma unroll
    for (int t2 = 0; t2 < 4; t2++) {
        const int d2 = t2 * 16 + lrow;
#pragma unroll
        for (int r = 0; r < 4; r++)
            Gh[(d1b + r) * 64 + d2] = g4[t2][r];
    }
}

// ---------------------------------------------------------------------------
// Weff (MFMA): WeffT[b][n][64h+d1] = scale * sum_d Wout[n][d+64h] * G[b,h][d][d1]
// G = Gpart[half0] + Gpart[half1] (fp32, deterministic). G symmetry -> both
// MFMA operands k-contiguous. Wout/G converted to bf16 in LDS.
// ---------------------------------------------------------------------------
__global__ __launch_bounds__(256)
void weff_kernel(const float* __restrict__ Wout, const float* __restrict__ Gpart,
                 __hip_bfloat16* __restrict__ WeffT) {
    const int n0 = blockIdx.x * 64;
    const int h  = blockIdx.y;
    const int b  = blockIdx.z;
    const float* G0 = Gpart + (long)((b * 16 + h) * 2 + 0) * 4096;
    const float* G1 = Gpart + (long)((b * 16 + h) * 2 + 1) * 4096;

    __shared__ __hip_bfloat16 Wl[64 * 72];
    __shared__ __hip_bfloat16 Gl[64 * 72];
    const int t = threadIdx.x;

#pragma unroll
    for (int it = 0; it < 4; it++) {
        const int ci = it * 256 + t;
        const int r = ci >> 4, c4 = (ci & 15) * 4;
        float4v v = (float4v){0.f, 0.f, 0.f, 0.f};
        if (n0 + r < NCLS)
            v = *(const float4v*)(Wout + (long)(n0 + r) * EMBED + h * HDIM + c4);
        *(uint2*)(Wl + r * 72 + c4) = (uint2){packbf2(v[0], v[1]), packbf2(v[2], v[3])};
        float4v g0 = *(const float4v*)(G0 + r * 64 + c4);
        float4v g1 = *(const float4v*)(G1 + r * 64 + c4);
        *(uint2*)(Gl + r * 72 + c4) =
            (uint2){packbf2(g0[0] + g1[0], g0[1] + g1[1]),
                    packbf2(g0[2] + g1[2], g0[3] + g1[3])};
    }
    __syncthreads();

    const int wave = t >> 6, lane = t & 63;
    const int lrow = lane & 15, lq = lane >> 4;
    float4v acc[4];
#pragma unroll
    for (int jj = 0; jj < 4; jj++) acc[jj] = (float4v){0.f, 0.f, 0.f, 0.f};

#pragma unroll
    for (int k0 = 0; k0 < 64; k0 += 32) {
        short8 af = *(const short8*)(Wl + (wave * 16 + lrow) * 72 + k0 + lq * 8);
#pragma unroll
        for (int jj = 0; jj < 4; jj++) {
            short8 bfr = *(const short8*)(Gl + (jj * 16 + lrow) * 72 + k0 + lq * 8);
            acc[jj] = __builtin_amdgcn_mfma_f32_16x16x32_bf16(af, bfr, acc[jj], 0, 0, 0);
        }
    }

    const float scale = 1.0f / 32.0f;  // 1/sqrt(EMBED)
    __hip_bfloat16* Wt = WeffT + (long)b * EMBED * NPAD;
#pragma unroll
    for (int jj = 0; jj < 4; jj++) {
        const int d1 = jj * 16 + lrow;
#pragma unroll
        for (int r = 0; r < 4; r++) {
            const int n = n0 + wave * 16 + lq * 4 + r;
            Wt[(long)n * EMBED + h * HDIM + d1] = __float2bfloat16(acc[jj][r] * scale);
        }
    }
}

// ---------------------------------------------------------------------------
extern "C" void kernel_launch(void* const* d_in, const int* in_sizes, int n_in,
                              void* d_out, int out_size, void* d_ws, size_t ws_size,
                              hipStream_t stream) {
    const float* x     = (const float*)d_in[0];
    const float* W_in  = (const float*)d_in[1];
    const float* b_in  = (const float*)d_in[2];
    const float* W_out = (const float*)d_in[3];
    const float* b_out = (const float*)d_in[4];
    float* out = (float*)d_out;

    char* ws = (char*)d_ws;
    __hip_bfloat16* xb    = (__hip_bfloat16*)(ws);                 // 8 MiB
    __hip_bfloat16* Winb  = (__hip_bfloat16*)(ws + (8u  << 20));   // 2 MiB
    __hip_bfloat16* P     = (__hip_bfloat16*)(ws + (10u << 20));   // 8 MiB
    float*          Gpart = (float*)(ws + (18u << 20));            // 1 MiB (64 x 16KiB)
    __hip_bfloat16* WeffT = (__hip_bfloat16*)(ws + (20u << 20));   // 4 MiB (2 batches)

    // 1) fp32->bf16 converts
    conv_inputs<<<(XN4 + WN4) / 256, 256, 0, stream>>>(x, W_in, xb, Winb);
    // 2) P = x @ W_in^T + b_in  [4096x1024] bf16
    gemm_bt_bias<__hip_bfloat16><<<1024, 256, 0, stream>>>(
        xb, Winb, b_in, P, NPAD, NPAD, 0);
    // 3) Gram partials (deterministic, no atomics)
    gram64<<<64, 256, 0, stream>>>(P, Gpart);
    // 4) WeffT[b] = scale * (G . Wout^T) per head block (MFMA)
    weff_kernel<<<dim3(16, 16, 2), 256, 0, stream>>>(W_out, Gpart, WeffT);
    // 5) out = P @ WeffT^T + b_out  [4096x1000] fp32, batch-strided B
    gemm_bt_bias<float><<<1024, 256, 0, stream>>>(
        P, WeffT, b_out, out, NCLS, NCLS, (long)EMBED * NPAD);
}

// Round 13
// 125.071 us; speedup vs baseline: 1.4593x; 1.0174x over previous
//
#include <hip/hip_runtime.h>
#include <hip/hip_bf16.h>
#include <cstdint>

#define EMBED   1024
#define NHEADS  16
#define HDIM    64
#define SEQ     2048
#define BSZ     2
#define MTOT    (BSZ*SEQ)   // 4096
#define NCLS    1000
#define NPAD    1024

typedef __attribute__((ext_vector_type(8))) short short8;
typedef __attribute__((ext_vector_type(4))) short short4v;
typedef __attribute__((ext_vector_type(4))) float float4v;

typedef __attribute__((address_space(3))) unsigned lds_uint;
typedef __attribute__((address_space(1))) const unsigned gbl_uint;

__device__ __forceinline__ void gl2lds16(const void* g, void* l) {
    __builtin_amdgcn_global_load_lds((gbl_uint*)g, (lds_uint*)l, 16, 0, 0);
}

#define WAITVM6() asm volatile("s_waitcnt vmcnt(6)" ::: "memory")
#define WAITVM0() asm volatile("s_waitcnt vmcnt(0)" ::: "memory")
#define BAR()     asm volatile("s_barrier" ::: "memory")

__device__ __forceinline__ void storeC(float* p, float v) { *p = v; }
__device__ __forceinline__ void storeC(__hip_bfloat16* p, float v) { *p = __float2bfloat16(v); }

__device__ __forceinline__ unsigned packbf2(float a, float b) {
    __hip_bfloat16 ha = __float2bfloat16(a), hb = __float2bfloat16(b);
    unsigned short ua, ub;
    __builtin_memcpy(&ua, &ha, 2); __builtin_memcpy(&ub, &hb, 2);
    return (unsigned)ua | ((unsigned)ub << 16);
}
// 8B-aligned LDS fragment load (row stride 68 bf16 = 136 B)
__device__ __forceinline__ short8 lds8u(const __hip_bfloat16* p) {
    union { uint2 u[2]; short8 s; } v;
    v.u[0] = *(const uint2*)p;
    v.u[1] = *(const uint2*)(p + 4);
    return v.s;
}

// ---------------------------------------------------------------------------
// Convert fp32 x, W_in to bf16 ws copies.
// ---------------------------------------------------------------------------
#define XN4  ((MTOT*EMBED)/4)    // 1,048,576
#define WN4  ((EMBED*EMBED)/4)   // 262,144
__global__ __launch_bounds__(256)
void conv_inputs(const float* __restrict__ x, const float* __restrict__ Win,
                 __hip_bfloat16* __restrict__ xb, __hip_bfloat16* __restrict__ Winb) {
    const long i4 = (long)blockIdx.x * 256 + threadIdx.x;  // float4 index
    float4v v;
    __hip_bfloat16* dst;
    if (i4 < XN4) {
        v = *(const float4v*)(x + i4 * 4);
        dst = xb + i4 * 4;
    } else {
        const long j = i4 - XN4;
        v = *(const float4v*)(Win + j * 4);
        dst = Winb + j * 4;
    }
    short4v o;
#pragma unroll
    for (int u = 0; u < 4; u++)
        ((__hip_bfloat16*)&o)[u] = __float2bfloat16(v[u]);
    *(short4v*)dst = o;
}

// ---------------------------------------------------------------------------
// GEMM: C[m][n] = sum_k A[m][k]*B[n][k] + bias[n]  (row-major, B^T input)
// 128x64 tile (wave ratio 0.75 -- best measured LDS traffic/FLOP), BK=64,
// 512 blocks = 2/CU, XOR-swizzled LDS, double-buffered s_barrier + vmcnt(6),
// XCD swizzle (per-XCD 3MB working set in its L2). Deterministic, no atomics.
// ---------------------------------------------------------------------------
template <typename CT>
__global__ __launch_bounds__(256)
void gemm_bt_bias(const __hip_bfloat16* __restrict__ A,
                  const __hip_bfloat16* __restrict__ B,
                  const float* __restrict__ bias,
                  CT* __restrict__ C,
                  int nstore, int cstride, long bstride) {
    __shared__ __hip_bfloat16 As[2][128 * 64];   // 2 x 16 KiB
    __shared__ __hip_bfloat16 Bs[2][64 * 64];    // 2 x  8 KiB

    const int t    = threadIdx.x;
    const int blk  = blockIdx.x;            // 0..511
    const int xcd  = blk & 7;
    const int j    = blk >> 3;              // 0..63
    const int bm   = (xcd * 4 + (j & 3)) * 128;
    const int bn   = (j >> 2) * 64;
    const __hip_bfloat16* Bb = B + (long)(bm >> 11) * bstride;
    const int wave = t >> 6, lane = t & 63;
    const int wm   = (wave & 1) * 64, wn = (wave >> 1) * 32;
    const int lrow = lane & 15, lq = lane >> 4;

    // staging map: chunk ci; LDS slot ci holds global
    // (row = ci>>3, k-chunk = (ci&7)^(row&7))  [16B chunks, 8 per 64-k row]
    const __hip_bfloat16* Arow[4];   // A: 1024 chunks, 4/thread
    const __hip_bfloat16* Brow[2];   // B: 512 chunks, 2/thread
#pragma unroll
    for (int i = 0; i < 4; i++) {
        const int ci = i * 256 + t;
        const int r  = ci >> 3;
        const int sc = ((ci & 7) ^ (r & 7)) * 8;
        Arow[i] = A + (long)(bm + r) * EMBED + sc;
    }
#pragma unroll
    for (int i = 0; i < 2; i++) {
        const int ci = i * 256 + t;
        const int r  = ci >> 3;
        const int sc = ((ci & 7) ^ (r & 7)) * 8;
        Brow[i] = Bb + (long)(bn + r) * EMBED + sc;
    }

    float4v acc[4][2];
#pragma unroll
    for (int i = 0; i < 4; i++)
#pragma unroll
        for (int jj = 0; jj < 2; jj++) acc[i][jj] = (float4v){0.f, 0.f, 0.f, 0.f};

    const int nIter = EMBED >> 6;   // 16

#define STAGE_TILE(k0, buf)                                                     \
    do {                                                                        \
        _Pragma("unroll")                                                       \
        for (int i = 0; i < 4; i++)                                             \
            gl2lds16(Arow[i] + (k0), (char*)As[buf] + (i * 256 + t) * 16);      \
        _Pragma("unroll")                                                       \
        for (int i = 0; i < 2; i++)                                             \
            gl2lds16(Brow[i] + (k0), (char*)Bs[buf] + (i * 256 + t) * 16);      \
    } while (0)

    STAGE_TILE(0, 0);

    for (int it = 0; it < nIter; ++it) {
        const int cur = it & 1, nxt = cur ^ 1;
        if (it + 1 < nIter) {
            STAGE_TILE((it + 1) << 6, nxt);
            WAITVM6();   // current tile's 6 loads done; prefetch in flight
        } else {
            WAITVM0();
        }
        BAR();           // tile `cur` staged for all waves

        const __hip_bfloat16* Ac = As[cur];
        const __hip_bfloat16* Bc = Bs[cur];
#pragma unroll
        for (int kk = 0; kk < 2; kk++) {
            short8 af[4], bf[2];
#pragma unroll
            for (int i = 0; i < 4; i++) {
                const int row = wm + i * 16 + lrow;
                const int sc  = (kk * 4 + lq) ^ (row & 7);
                af[i] = *(const short8*)(Ac + row * 64 + sc * 8);
            }
#pragma unroll
            for (int jj = 0; jj < 2; jj++) {
                const int row = wn + jj * 16 + lrow;
                const int sc  = (kk * 4 + lq) ^ (row & 7);
                bf[jj] = *(const short8*)(Bc + row * 64 + sc * 8);
            }
#pragma unroll
            for (int i = 0; i < 4; i++)
#pragma unroll
                for (int jj = 0; jj < 2; jj++)
                    acc[i][jj] = __builtin_amdgcn_mfma_f32_16x16x32_bf16(af[i], bf[jj], acc[i][jj], 0, 0, 0);
        }
        BAR();           // all waves done reading `cur` before it's overwritten
    }
#undef STAGE_TILE

    // epilogue: C/D layout col=lane&15, row=lq*4+reg
    float bv[2];
#pragma unroll
    for (int jj = 0; jj < 2; jj++) {
        const int gn = bn + wn + jj * 16 + lrow;
        bv[jj] = (gn < nstore) ? bias[gn] : 0.f;
    }
#pragma unroll
    for (int i = 0; i < 4; i++) {
        const int gm0 = bm + wm + i * 16 + lq * 4;
#pragma unroll
        for (int jj = 0; jj < 2; jj++) {
            const int gn = bn + wn + jj * 16 + lrow;
            if (gn < nstore) {
#pragma unroll
                for (int r = 0; r < 4; r++)
                    storeC(&C[(long)(gm0 + r) * cstride + gn], acc[i][jj][r] + bv[jj]);
            }
        }
    }
}

// ---------------------------------------------------------------------------
// gram128: DETERMINISTIC Gram partials, no atomics, 128 blocks (2x CU
// coverage of gram64). blk -> (bh = blk>>2, q = blk&3); block owns 512 seq
// rows of head h, stages 64-row chunks transposed into LDS (Pt[d][m]),
// accumulates its 64x64 partial via MFMA in registers, writes Gpart[blk].
// ---------------------------------------------------------------------------
__global__ __launch_bounds__(256)
void gram128(const __hip_bfloat16* __restrict__ P, float* __restrict__ Gpart) {
    __shared__ __hip_bfloat16 Pt[64 * 68];   // [d][m], 8.5 KiB
    const int t    = threadIdx.x;
    const int blk  = blockIdx.x;             // 0..127
    const int bh   = blk >> 2;               // 0..31
    const int q    = blk & 3;
    const int b    = bh >> 4, h = bh & 15;
    const int row0 = b * SEQ + q * 512;

    const int wave = t >> 6, lane = t & 63;
    const int lrow = lane & 15, lq = lane >> 4;

    float4v g4[4];
#pragma unroll
    for (int t2 = 0; t2 < 4; t2++) g4[t2] = (float4v){0.f, 0.f, 0.f, 0.f};

    for (int c = 0; c < 8; c++) {            // 8 chunks of 64 rows
#pragma unroll
        for (int i = 0; i < 2; i++) {
            const int ci = i * 256 + t;
            const int r = ci >> 3, c8 = (ci & 7) * 8;   // row-in-chunk, d-offset
            short8 v = *(const short8*)(P + (long)(row0 + c * 64 + r) * EMBED + h * HDIM + c8);
#pragma unroll
            for (int u = 0; u < 8; u++)
                Pt[(c8 + u) * 68 + r] = ((const __hip_bfloat16*)&v)[u];
        }
        __syncthreads();

#pragma unroll
        for (int k0 = 0; k0 < 64; k0 += 32) {
            short8 af = lds8u(Pt + (wave * 16 + lrow) * 68 + k0 + lq * 8);
#pragma unroll
            for (int t2 = 0; t2 < 4; t2++) {
                short8 bfr = lds8u(Pt + (t2 * 16 + lrow) * 68 + k0 + lq * 8);
                g4[t2] = __builtin_amdgcn_mfma_f32_16x16x32_bf16(af, bfr, g4[t2], 0, 0, 0);
            }
        }
        __syncthreads();
    }

    // store partial: C/D layout col=lane&15 (d2), row=lq*4+reg (d1 band)
    float* Gh = Gpart + (long)blk * 4096;
    const int d1b = wave * 16 + lq * 4;
#pragma unroll
    for (int t2 = 0; t2 < 4; t2++) {
        const int d2 = t2 * 16 + lrow;
#pragma unroll
        for (int r = 0; r < 4; r++)
            Gh[(d1b + r) * 64 + d2] = g4[t2][r];
    }
}

// ---------------------------------------------------------------------------
// Weff (MFMA): WeffT[b][n][64h+d1] = scale * sum_d Wout[n][d+64h] * G[b,h][d][d1]
// G = sum of 4 Gpart slots (fp32, fixed order -> deterministic). G symmetry
// makes both MFMA operands k-contiguous. Wout/G converted to bf16 in LDS.
// ---------------------------------------------------------------------------
__global__ __launch_bounds__(256)
void weff_kernel(const float* __restrict__ Wout, const float* __restrict__ Gpart,
                 __hip_bfloat16* __restrict__ WeffT) {
    const int n0 = blockIdx.x * 64;
    const int h  = blockIdx.y;
    const int b  = blockIdx.z;
    const float* G0 = Gpart + (long)((b * 16 + h) * 4 + 0) * 4096;
    const float* G1 = Gpart + (long)((b * 16 + h) * 4 + 1) * 4096;
    const float* G2 = Gpart + (long)((b * 16 + h) * 4 + 2) * 4096;
    const float* G3 = Gpart + (long)((b * 16 + h) * 4 + 3) * 4096;

    __shared__ __hip_bfloat16 Wl[64 * 72];
    __shared__ __hip_bfloat16 Gl[64 * 72];
    const int t = threadIdx.x;

#pragma unroll
    for (int it = 0; it < 4; it++) {
        const int ci = it * 256 + t;
        const int r = ci >> 4, c4 = (ci & 15) * 4;
        float4v v = (float4v){0.f, 0.f, 0.f, 0.f};
        if (n0 + r < NCLS)
            v = *(const float4v*)(Wout + (long)(n0 + r) * EMBED + h * HDIM + c4);
        *(uint2*)(Wl + r * 72 + c4) = (uint2){packbf2(v[0], v[1]), packbf2(v[2], v[3])};
        float4v g0 = *(const float4v*)(G0 + r * 64 + c4);
        float4v g1 = *(const float4v*)(G1 + r * 64 + c4);
        float4v g2 = *(const float4v*)(G2 + r * 64 + c4);
        float4v g3 = *(const float4v*)(G3 + r * 64 + c4);
        float4v gs;
#pragma unroll
        for (int u = 0; u < 4; u++) gs[u] = ((g0[u] + g1[u]) + g2[u]) + g3[u];
        *(uint2*)(Gl + r * 72 + c4) = (uint2){packbf2(gs[0], gs[1]), packbf2(gs[2], gs[3])};
    }
    __syncthreads();

    const int wave = t >> 6, lane = t & 63;
    const int lrow = lane & 15, lq = lane >> 4;
    float4v acc[4];
#pragma unroll
    for (int jj = 0; jj < 4; jj++) acc[jj] = (float4v){0.f, 0.f, 0.f, 0.f};

#pragma unroll
    for (int k0 = 0; k0 < 64; k0 += 32) {
        short8 af = *(const short8*)(Wl + (wave * 16 + lrow) * 72 + k0 + lq * 8);
#pragma unroll
        for (int jj = 0; jj < 4; jj++) {
            short8 bfr = *(const short8*)(Gl + (jj * 16 + lrow) * 72 + k0 + lq * 8);
            acc[jj] = __builtin_amdgcn_mfma_f32_16x16x32_bf16(af, bfr, acc[jj], 0, 0, 0);
        }
    }

    const float scale = 1.0f / 32.0f;  // 1/sqrt(EMBED)
    __hip_bfloat16* Wt = WeffT + (long)b * EMBED * NPAD;
#pragma unroll
    for (int jj = 0; jj < 4; jj++) {
        const int d1 = jj * 16 + lrow;
#pragma unroll
        for (int r = 0; r < 4; r++) {
            const int n = n0 + wave * 16 + lq * 4 + r;
            Wt[(long)n * EMBED + h * HDIM + d1] = __float2bfloat16(acc[jj][r] * scale);
        }
    }
}

// ---------------------------------------------------------------------------
extern "C" void kernel_launch(void* const* d_in, const int* in_sizes, int n_in,
                              void* d_out, int out_size, void* d_ws, size_t ws_size,
                              hipStream_t stream) {
    const float* x     = (const float*)d_in[0];
    const float* W_in  = (const float*)d_in[1];
    const float* b_in  = (const float*)d_in[2];
    const float* W_out = (const float*)d_in[3];
    const float* b_out = (const float*)d_in[4];
    float* out = (float*)d_out;

    char* ws = (char*)d_ws;
    __hip_bfloat16* xb    = (__hip_bfloat16*)(ws);                 // 8 MiB
    __hip_bfloat16* Winb  = (__hip_bfloat16*)(ws + (8u  << 20));   // 2 MiB
    __hip_bfloat16* P     = (__hip_bfloat16*)(ws + (10u << 20));   // 8 MiB
    float*          Gpart = (float*)(ws + (18u << 20));            // 2 MiB (128 x 16KiB)
    __hip_bfloat16* WeffT = (__hip_bfloat16*)(ws + (20u << 20));   // 4 MiB (2 batches)

    // 1) fp32->bf16 converts
    conv_inputs<<<(XN4 + WN4) / 256, 256, 0, stream>>>(x, W_in, xb, Winb);
    // 2) P = x @ W_in^T + b_in  [4096x1024] bf16  (128x64 tiles, 2/CU)
    gemm_bt_bias<__hip_bfloat16><<<512, 256, 0, stream>>>(
        xb, Winb, b_in, P, NPAD, NPAD, 0);
    // 3) Gram partials (deterministic, 128 blocks)
    gram128<<<128, 256, 0, stream>>>(P, Gpart);
    // 4) WeffT[b] = scale * (G . Wout^T) per head block (MFMA)
    weff_kernel<<<dim3(16, 16, 2), 256, 0, stream>>>(W_out, Gpart, WeffT);
    // 5) out = P @ WeffT^T + b_out  [4096x1000] fp32, batch-strided B
    gemm_bt_bias<float><<<512, 256, 0, stream>>>(
        P, WeffT, b_out, out, NCLS, NCLS, (long)EMBED * NPAD);
}